// Round 3
// baseline (2818.245 us; speedup 1.0000x reference)
//
#include <hip/hip_runtime.h>
#include <hip/hip_bf16.h>

#define HWN 65536
#define WN 256
#define HN 256
#define CN 64
#define DWN 128

// ---- workspace layout (floats) — total < 1 MiB ----
#define W1N_OFF 0
#define W2N_OFF 65536
#define W3N_OFF 74752
#define W4N_OFF 107520
#define W5N_OFF 173056
#define POOL_OFF 205824
#define SCA_OFF 206336

__device__ __forceinline__ void norm_row(const float* __restrict__ in,
                                         float* __restrict__ out, int n) {
    float s = 0.f;
    for (int i = 0; i < n; i++) { float v = in[i]; s += v * v; }
    float r = rsqrtf(s);
    for (int i = 0; i < n; i++) out[i] = in[i] * r;
}

__global__ void k_prep(const float* __restrict__ w1, const float* __restrict__ w2,
                       const float* __restrict__ w3, const float* __restrict__ w4,
                       const float* __restrict__ w5, float* __restrict__ ws) {
    int r = blockIdx.x * 256 + threadIdx.x;
    if (r < 1024) {
        norm_row(w1 + r * 64, ws + W1N_OFF + r * 64, 64);
    } else if (r < 2048) {
        int rr = r - 1024;
        norm_row(w2 + rr * 9, ws + W2N_OFF + rr * 9, 9);
    } else if (r < 2560) {
        int rr = r - 2048;
        norm_row(w3 + rr * 64, ws + W3N_OFF + rr * 64, 64);
    } else if (r < 3584) {
        int rr = r - 2560;
        norm_row(w4 + rr * 64, ws + W4N_OFF + rr * 64, 64);
    } else if (r < 4096) {
        int rr = r - 3584;
        norm_row(w5 + rr * 64, ws + W5N_OFF + rr * 64, 64);
    } else if (r < 4608) {
        ws[POOL_OFF + (r - 4096)] = 0.f;
    }
}

// Fused: LN1 + pw1 + dw3x3 + SimpleGate + pooled-sum -> g (d_out as scratch, fp32)
// 384 threads/block. Threads 0..323 own one 18x18-halo pixel, LN1-normalized
// x[64] kept in VGPRs. Per channel pair (c, c+64): halo threads compute the
// pw1 dot into LDS, then threads 0..255 do the 3x3 dw conv + gate on the tile.
__global__ __launch_bounds__(384) void k_ab(
    const float* __restrict__ inp, const float* __restrict__ ln1w,
    const float* __restrict__ ln1b, const float* __restrict__ b1,
    const float* __restrict__ w1n, const float* __restrict__ w2n,
    const float* __restrict__ b2v, float* __restrict__ pooled,
    float* __restrict__ g) {
    const int b = blockIdx.x >> 8;
    const int tile = blockIdx.x & 255;
    const int x0 = (tile & 15) * 16, y0 = (tile >> 4) * 16;
    const int e = threadIdx.x;
    __shared__ float sA[324];
    __shared__ float sB[324];

    float xn[64];
    bool inb = false;
    if (e < 324) {
        int hy = e / 18, hx = e - hy * 18;
        int yy = y0 - 1 + hy, xx = x0 - 1 + hx;
        inb = (yy >= 0 && yy < HN && xx >= 0 && xx < WN);
        if (inb) {
            const float* xin = inp + ((size_t)b * CN) * HWN + yy * WN + xx;
            float s = 0.f, s2 = 0.f;
#pragma unroll
            for (int c = 0; c < 64; c++) {
                float v = xin[(size_t)c * HWN];
                xn[c] = v; s += v; s2 += v * v;
            }
            float mu = s * (1.f / 64.f);
            float var = s2 * (1.f / 64.f) - mu * mu;
            float rr = rsqrtf(var + 1e-6f);
#pragma unroll
            for (int c = 0; c < 64; c++)
                xn[c] = (xn[c] - mu) * rr * ln1w[c] + ln1b[c];
        }
    }
    const int lx = threadIdx.x & 15;
    const int ly = (threadIdx.x >> 4) & 15;

    for (int c = 0; c < 64; c++) {
        if (e < 324) {
            float a = 0.f, q = 0.f;
            if (inb) {
                const float* wA = w1n + (b * DWN + c) * 64;
                const float* wB = w1n + (b * DWN + c + 64) * 64;
                a = b1[b * DWN + c];
                q = b1[b * DWN + c + 64];
#pragma unroll
                for (int k = 0; k < 64; k++) {
                    a += xn[k] * wA[k];
                    q += xn[k] * wB[k];
                }
            }
            sA[e] = a;
            sB[e] = q;
        }
        __syncthreads();
        if (threadIdx.x < 256) {
            const float* w2A = w2n + (b * DWN + c) * 9;
            const float* w2B = w2n + (b * DWN + c + 64) * 9;
            float a = b2v[b * DWN + c];
            float q = b2v[b * DWN + c + 64];
#pragma unroll
            for (int ky = 0; ky < 3; ky++)
#pragma unroll
                for (int kx = 0; kx < 3; kx++) {
                    a += sA[(ly + ky) * 18 + lx + kx] * w2A[ky * 3 + kx];
                    q += sB[(ly + ky) * 18 + lx + kx] * w2B[ky * 3 + kx];
                }
            float gv = a * q;
            g[((size_t)b * 64 + c) * HWN + (y0 + ly) * WN + (x0 + lx)] = gv;
            float v = gv;
#pragma unroll
            for (int off = 32; off; off >>= 1) v += __shfl_down(v, off);
            if ((threadIdx.x & 63) == 0) atomicAdd(&pooled[b * 64 + c], v);
        }
        __syncthreads();
    }
}

__global__ void k_sca(const float* __restrict__ pooled,
                      const float* __restrict__ scaw,
                      const float* __restrict__ scab,
                      float* __restrict__ sca) {
    int t = threadIdx.x;  // 512 = 8*64
    int b = t >> 6, o = t & 63;
    float acc = scab[o];
    for (int c = 0; c < 64; c++)
        acc += pooled[b * 64 + c] * (1.f / 65536.f) * scaw[o * 64 + c];
    sca[t] = acc;
}

// x*sca -> pw3 -> y=inp+x*beta -> LN2 -> pw4 -> gate -> pw5 -> out=y+x*gamma
// g and out alias (d_out, fp32); each thread reads its pixel fully before writing.
__global__ __launch_bounds__(256) void k_d(
    const float* __restrict__ inp, const float* g,
    const float* __restrict__ sca,
    const float* __restrict__ w3n, const float* __restrict__ b3,
    const float* __restrict__ beta,
    const float* __restrict__ ln2w, const float* __restrict__ ln2b,
    const float* __restrict__ w4n, const float* __restrict__ b4,
    const float* __restrict__ w5n, const float* __restrict__ b5,
    const float* __restrict__ gamma, float* out) {
    const int b = blockIdx.x >> 8;
    const int p = ((blockIdx.x & 255) << 8) | threadIdx.x;

    float x[64];
#pragma unroll
    for (int c = 0; c < 64; c++)
        x[c] = g[((size_t)b * 64 + c) * HWN + p] * sca[b * 64 + c];

    float y[64];
    const float* w3row = w3n + b * 64 * 64;
    const float* irow = inp + (size_t)b * 64 * HWN + p;
    for (int o = 0; o < 64; o += 4) {
        float a0 = b3[b * 64 + o + 0];
        float a1 = b3[b * 64 + o + 1];
        float a2 = b3[b * 64 + o + 2];
        float a3 = b3[b * 64 + o + 3];
#pragma unroll
        for (int c = 0; c < 64; c++) {
            float xc = x[c];
            a0 += xc * w3row[(o + 0) * 64 + c];
            a1 += xc * w3row[(o + 1) * 64 + c];
            a2 += xc * w3row[(o + 2) * 64 + c];
            a3 += xc * w3row[(o + 3) * 64 + c];
        }
        y[o + 0] = irow[(size_t)(o + 0) * HWN] + a0 * beta[o + 0];
        y[o + 1] = irow[(size_t)(o + 1) * HWN] + a1 * beta[o + 1];
        y[o + 2] = irow[(size_t)(o + 2) * HWN] + a2 * beta[o + 2];
        y[o + 3] = irow[(size_t)(o + 3) * HWN] + a3 * beta[o + 3];
    }

    // LN2 (reuse x[] for normalized values)
    {
        float s = 0.f, s2 = 0.f;
#pragma unroll
        for (int c = 0; c < 64; c++) { s += y[c]; s2 += y[c] * y[c]; }
        float mu = s * (1.f / 64.f);
        float var = s2 * (1.f / 64.f) - mu * mu;
        float rr = rsqrtf(var + 1e-6f);
#pragma unroll
        for (int c = 0; c < 64; c++)
            x[c] = (y[c] - mu) * rr * ln2w[c] + ln2b[c];
    }

    // pw4 + gate
    float h[64];
    const float* w4row = w4n + b * 128 * 64;
    for (int c = 0; c < 64; c += 2) {
        float a0 = b4[b * 128 + c];
        float a1 = b4[b * 128 + c + 1];
        float q0 = b4[b * 128 + 64 + c];
        float q1 = b4[b * 128 + 64 + c + 1];
#pragma unroll
        for (int k = 0; k < 64; k++) {
            float xk = x[k];
            a0 += xk * w4row[(c + 0) * 64 + k];
            a1 += xk * w4row[(c + 1) * 64 + k];
            q0 += xk * w4row[(64 + c + 0) * 64 + k];
            q1 += xk * w4row[(64 + c + 1) * 64 + k];
        }
        h[c + 0] = a0 * q0;
        h[c + 1] = a1 * q1;
    }

    // pw5 + out
    const float* w5row = w5n + b * 64 * 64;
    for (int o = 0; o < 64; o += 4) {
        float a0 = b5[b * 64 + o + 0];
        float a1 = b5[b * 64 + o + 1];
        float a2 = b5[b * 64 + o + 2];
        float a3 = b5[b * 64 + o + 3];
#pragma unroll
        for (int c = 0; c < 64; c++) {
            float hc = h[c];
            a0 += hc * w5row[(o + 0) * 64 + c];
            a1 += hc * w5row[(o + 1) * 64 + c];
            a2 += hc * w5row[(o + 2) * 64 + c];
            a3 += hc * w5row[(o + 3) * 64 + c];
        }
        out[((size_t)b * 64 + o + 0) * HWN + p] = y[o + 0] + a0 * gamma[o + 0];
        out[((size_t)b * 64 + o + 1) * HWN + p] = y[o + 1] + a1 * gamma[o + 1];
        out[((size_t)b * 64 + o + 2) * HWN + p] = y[o + 2] + a2 * gamma[o + 2];
        out[((size_t)b * 64 + o + 3) * HWN + p] = y[o + 3] + a3 * gamma[o + 3];
    }
}

extern "C" void kernel_launch(void* const* d_in, const int* in_sizes, int n_in,
                              void* d_out, int out_size, void* d_ws, size_t ws_size,
                              hipStream_t stream) {
    const float* inp  = (const float*)d_in[0];
    const float* w1   = (const float*)d_in[1];
    const float* b1   = (const float*)d_in[2];
    const float* w2   = (const float*)d_in[3];
    const float* b2v  = (const float*)d_in[4];
    const float* w3   = (const float*)d_in[5];
    const float* b3   = (const float*)d_in[6];
    const float* w4   = (const float*)d_in[7];
    const float* b4   = (const float*)d_in[8];
    const float* w5   = (const float*)d_in[9];
    const float* b5   = (const float*)d_in[10];
    const float* ln1w = (const float*)d_in[11];
    const float* ln1b = (const float*)d_in[12];
    const float* ln2w = (const float*)d_in[13];
    const float* ln2b = (const float*)d_in[14];
    const float* scaw = (const float*)d_in[15];
    const float* scab = (const float*)d_in[16];
    const float* beta = (const float*)d_in[17];
    const float* gamma= (const float*)d_in[18];

    float* ws = (float*)d_ws;
    float* w1n = ws + W1N_OFF;
    float* w2n = ws + W2N_OFF;
    float* w3n = ws + W3N_OFF;
    float* w4n = ws + W4N_OFF;
    float* w5n = ws + W5N_OFF;
    float* pooled = ws + POOL_OFF;
    float* sca = ws + SCA_OFF;
    float* g = (float*)d_out;   // d_out doubles as scratch for the gated tensor
    float* out = (float*)d_out;

    k_prep<<<18, 256, 0, stream>>>(w1, w2, w3, w4, w5, ws);
    k_ab<<<2048, 384, 0, stream>>>(inp, ln1w, ln1b, b1, w1n, w2n, b2v, pooled, g);
    k_sca<<<1, 512, 0, stream>>>(pooled, scaw, scab, sca);
    k_d<<<2048, 256, 0, stream>>>(inp, g, sca, w3n, b3, beta, ln2w, ln2b,
                                  w4n, b4, w5n, b5, gamma, out);
}

// Round 4
// 837.991 us; speedup vs baseline: 3.3631x; 3.3631x over previous
//
#include <hip/hip_runtime.h>
#include <hip/hip_bf16.h>

typedef __attribute__((ext_vector_type(8))) short short8;
typedef __attribute__((ext_vector_type(4))) float f32x4;

#define HWN 65536
#define WN 256
#define HN 256

// ws float offsets (total < 1 MiB)
#define W1N_OFF 0
#define W2N_OFF 65536
#define W3N_OFF 74752
#define W4N_OFF 107520
#define W5N_OFF 173056
#define POOL_OFF 205824
#define SCA_OFF 206336

static __device__ __forceinline__ short f2bs(float f) {
    union { __hip_bfloat16 h; short s; } u; u.h = __float2bfloat16(f); return u.s;
}
static __device__ __forceinline__ float bs2f(short s) {
    union { unsigned u; float f; } v; v.u = ((unsigned)(unsigned short)s) << 16; return v.f;
}

__device__ __forceinline__ void norm_row(const float* __restrict__ in,
                                         float* __restrict__ out, int n) {
    float s = 0.f;
    for (int i = 0; i < n; i++) { float v = in[i]; s += v * v; }
    float r = rsqrtf(s);
    for (int i = 0; i < n; i++) out[i] = in[i] * r;
}

__global__ void k_prep(const float* __restrict__ w1, const float* __restrict__ w2,
                       const float* __restrict__ w3, const float* __restrict__ w4,
                       const float* __restrict__ w5, float* __restrict__ ws) {
    int r = blockIdx.x * 256 + threadIdx.x;
    if (r < 1024) {
        norm_row(w1 + r * 64, ws + W1N_OFF + r * 64, 64);
    } else if (r < 2048) {
        int rr = r - 1024;
        norm_row(w2 + rr * 9, ws + W2N_OFF + rr * 9, 9);
    } else if (r < 2560) {
        int rr = r - 2048;
        norm_row(w3 + rr * 64, ws + W3N_OFF + rr * 64, 64);
    } else if (r < 3584) {
        int rr = r - 2560;
        norm_row(w4 + rr * 64, ws + W4N_OFF + rr * 64, 64);
    } else if (r < 4096) {
        int rr = r - 3584;
        norm_row(w5 + rr * 64, ws + W5N_OFF + rr * 64, 64);
    }
}

// LN1 + pw1(MFMA) + dw3x3 + gate -> g (d_out as scratch)
__global__ __launch_bounds__(256, 2) void k1(
    const float* __restrict__ inp, const float* __restrict__ ln1w,
    const float* __restrict__ ln1b, const float* __restrict__ b1,
    const float* __restrict__ b2v, const float* __restrict__ ws,
    float* __restrict__ g) {
    const float* w1n = ws + W1N_OFF;
    const float* w2n = ws + W2N_OFF;
    const int b = blockIdx.x >> 8;
    const int tile = blockIdx.x & 255;
    const int x0 = (tile & 15) << 4, y0 = (tile >> 4) << 4;
    const int t = threadIdx.x;
    const int wave = t >> 6, lane = t & 63;
    const int n = lane & 15, q = lane >> 4;

    __shared__ short sXn[336 * 72];  // bf16 [halo_pix][ch], stride 72 (144B, 16B-mult)
    __shared__ short sP[324 * 24];   // bf16 [halo_pix][16 out-ch], stride 24 (48B)

    // phase A: LN1 over 64 ch for each of 324 halo pixels -> sXn (bf16)
    for (int pix = t; pix < 324; pix += 256) {
        int hy = pix / 18, hx = pix - hy * 18;
        int yy = y0 - 1 + hy, xx = x0 - 1 + hx;
        bool inb = ((unsigned)yy < HN) && ((unsigned)xx < WN);
        const float* xin = inp + ((size_t)b << 22) + (yy * WN + xx);
        float s = 0.f, s2 = 0.f;
#pragma unroll
        for (int c = 0; c < 64; c++) {
            float v = inb ? xin[(size_t)c << 16] : 0.f;
            s += v; s2 += v * v;
            sXn[pix * 72 + c] = f2bs(v);
        }
        float mu = s * (1.f / 64.f);
        float var = s2 * (1.f / 64.f) - mu * mu;
        float rr = rsqrtf(var + 1e-6f);
        for (int c = 0; c < 64; c++) {
            float xv = bs2f(sXn[pix * 72 + c]);
            sXn[pix * 72 + c] = f2bs((xv - mu) * rr * ln1w[c] + ln1b[c]);
        }
    }
    for (int i = t; i < 12 * 72; i += 256) sXn[324 * 72 + i] = 0;  // M-pad rows
    __syncthreads();

    const float* w1b = w1n + b * 128 * 64;
    const float* w2b = w2n + b * 128 * 9;
    const float* b1b = b1 + b * 128;
    const float* b2b = b2v + b * 128;
    const int lx = t & 15, ly = t >> 4;

    for (int cc = 0; cc < 8; cc++) {
        // B fragment: cols n<8 -> out ch cc*8+n ; n>=8 -> cc*8+64+(n-8)
        int outch = cc * 8 + (n < 8 ? n : 56 + n);
        short8 bf0, bf1;
        {
            const float* wp = w1b + outch * 64 + q * 8;
#pragma unroll
            for (int j = 0; j < 8; j++) bf0[j] = f2bs(wp[j]);
            wp += 32;
#pragma unroll
            for (int j = 0; j < 8; j++) bf1[j] = f2bs(wp[j]);
        }
        float bias = b1b[outch];
        for (int mt = wave; mt < 21; mt += 4) {
            const short* arow = &sXn[(mt * 16 + n) * 72];
            short8 a0 = *(const short8*)(arow + q * 8);
            short8 a1 = *(const short8*)(arow + 32 + q * 8);
            f32x4 d = {0.f, 0.f, 0.f, 0.f};
            d = __builtin_amdgcn_mfma_f32_16x16x32_bf16(a0, bf0, d, 0, 0, 0);
            d = __builtin_amdgcn_mfma_f32_16x16x32_bf16(a1, bf1, d, 0, 0, 0);
#pragma unroll
            for (int r = 0; r < 4; r++) {
                int row = mt * 16 + q * 4 + r;
                if (row < 324) sP[row * 24 + n] = f2bs(d[r] + bias);
            }
        }
        __syncthreads();
        // dw 3x3 + gate on the 16x16 tile for pairs cc*8 .. cc*8+7
        float accA[8], accB[8];
#pragma unroll
        for (int p = 0; p < 8; p++) {
            accA[p] = b2b[cc * 8 + p];
            accB[p] = b2b[64 + cc * 8 + p];
        }
#pragma unroll
        for (int ky = 0; ky < 3; ky++) {
#pragma unroll
            for (int kx = 0; kx < 3; kx++) {
                int yy = y0 + ly + ky - 1, xx = x0 + lx + kx - 1;
                bool valid = ((unsigned)yy < HN) && ((unsigned)xx < WN);
                int e = (ly + ky) * 18 + lx + kx;
                short8 pA = *(const short8*)&sP[e * 24];
                short8 pB = *(const short8*)&sP[e * 24 + 8];
#pragma unroll
                for (int p = 0; p < 8; p++) {
                    float va = valid ? bs2f(pA[p]) : 0.f;
                    float vb = valid ? bs2f(pB[p]) : 0.f;
                    accA[p] += va * w2b[(cc * 8 + p) * 9 + ky * 3 + kx];
                    accB[p] += vb * w2b[(64 + cc * 8 + p) * 9 + ky * 3 + kx];
                }
            }
        }
        size_t gbase = ((size_t)(b * 64 + cc * 8)) * HWN + (size_t)((y0 + ly) * WN + x0 + lx);
#pragma unroll
        for (int p = 0; p < 8; p++)
            g[gbase + ((size_t)p << 16)] = accA[p] * accB[p];
        __syncthreads();
    }
}

// pooled[b][c] = sum over pixels of g  (one block per (b,c) — no atomics)
__global__ __launch_bounds__(1024) void k_pool(const float* __restrict__ g,
                                               float* __restrict__ pooled) {
    int bc = blockIdx.x;  // 0..511
    const float* src = g + (size_t)bc * HWN;
    float s = 0.f;
    for (int i = threadIdx.x * 4; i < HWN; i += 4096) {
        f32x4 v = *(const f32x4*)&src[i];
        s += v[0] + v[1] + v[2] + v[3];
    }
    __shared__ float red[16];
    int lane = threadIdx.x & 63, wave = threadIdx.x >> 6;
#pragma unroll
    for (int off = 32; off; off >>= 1) s += __shfl_down(s, off);
    if (lane == 0) red[wave] = s;
    __syncthreads();
    if (threadIdx.x < 16) {
        float v = red[threadIdx.x];
#pragma unroll
        for (int off = 8; off; off >>= 1) v += __shfl_down(v, off);
        if (threadIdx.x == 0) pooled[bc] = v;
    }
}

__global__ void k_sca(const float* __restrict__ pooled,
                      const float* __restrict__ scaw,
                      const float* __restrict__ scab,
                      float* __restrict__ sca) {
    int t = threadIdx.x;  // 512 = 8*64
    int b = t >> 6, o = t & 63;
    float acc = scab[o];
    for (int c = 0; c < 64; c++)
        acc += pooled[b * 64 + c] * (1.f / 65536.f) * scaw[o * 64 + c];
    sca[t] = acc;
}

// x=g*sca -> pw3(MFMA) -> y=inp+beta*x3 -> LN2 -> pw4(MFMA)+gate -> pw5(MFMA)
// -> out = y + gamma*x5.  g and out alias (d_out); block reads its own pixels
// in phase 1, writes them only in phase 6.
__global__ __launch_bounds__(256, 2) void k2(
    const float* __restrict__ inp, const float* g, const float* __restrict__ ws,
    const float* __restrict__ b3, const float* __restrict__ beta,
    const float* __restrict__ ln2w, const float* __restrict__ ln2b,
    const float* __restrict__ b4, const float* __restrict__ b5,
    const float* __restrict__ gamma, float* out) {
    const int b = blockIdx.x >> 9;
    const int px0 = (blockIdx.x & 511) << 7;  // 128 pixels per block
    const int t = threadIdx.x;
    const int wave = t >> 6, lane = t & 63;
    const int n = lane & 15, q = lane >> 4;

    __shared__ short sX[128 * 72];  // bf16 A-operand staging
    __shared__ short sY[64 * 136];  // bf16 y [ch][px]
    __shared__ short sH[128 * 72];  // bf16 h staging

    const float* scav = ws + SCA_OFF + b * 64;

    // phase 1: xg = g * sca -> sX
    {
        const float* gb = g + ((size_t)b << 22) + px0;
        for (int i = t; i < 128 * 64; i += 256) {
            int c = i >> 7, px = i & 127;
            sX[px * 72 + c] = f2bs(gb[((size_t)c << 16) + px] * scav[c]);
        }
    }
    __syncthreads();

    // phase 2: pw3 -> y -> sY
    {
        const float* w3b = ws + W3N_OFF + b * 64 * 64;
        const float* b3b = b3 + b * 64;
        for (int nc = 0; nc < 4; nc++) {
            int outch = nc * 16 + n;
            short8 bf0, bf1;
            const float* wp = w3b + outch * 64 + q * 8;
#pragma unroll
            for (int j = 0; j < 8; j++) bf0[j] = f2bs(wp[j]);
            wp += 32;
#pragma unroll
            for (int j = 0; j < 8; j++) bf1[j] = f2bs(wp[j]);
            float b3v = b3b[outch], betav = beta[outch];
            const float* ib = inp + ((size_t)b << 22) + ((size_t)outch << 16) + px0;
            for (int mt = wave; mt < 8; mt += 4) {
                const short* arow = &sX[(mt * 16 + n) * 72];
                short8 a0 = *(const short8*)(arow + q * 8);
                short8 a1 = *(const short8*)(arow + 32 + q * 8);
                f32x4 d = {0.f, 0.f, 0.f, 0.f};
                d = __builtin_amdgcn_mfma_f32_16x16x32_bf16(a0, bf0, d, 0, 0, 0);
                d = __builtin_amdgcn_mfma_f32_16x16x32_bf16(a1, bf1, d, 0, 0, 0);
#pragma unroll
                for (int r = 0; r < 4; r++) {
                    int px = mt * 16 + q * 4 + r;
                    float y = ib[px] + betav * (d[r] + b3v);
                    sY[outch * 136 + px] = f2bs(y);
                }
            }
        }
    }
    __syncthreads();

    // phase 3: LN2 per pixel -> sX (normalized, bf16)
    if (t < 128) {
        float s = 0.f, s2 = 0.f;
        for (int c = 0; c < 64; c++) {
            float v = bs2f(sY[c * 136 + t]);
            s += v; s2 += v * v;
        }
        float mu = s * (1.f / 64.f);
        float var = s2 * (1.f / 64.f) - mu * mu;
        float rr = rsqrtf(var + 1e-6f);
        for (int c = 0; c < 64; c++) {
            float xn = (bs2f(sY[c * 136 + t]) - mu) * rr * ln2w[c] + ln2b[c];
            sX[t * 72 + c] = f2bs(xn);
        }
    }
    __syncthreads();

    // phase 4: pw4 + gate -> sH
    {
        const float* w4b = ws + W4N_OFF + b * 128 * 64;
        const float* b4b = b4 + b * 128;
        for (int cc = 0; cc < 8; cc++) {
            int outch = cc * 8 + (n < 8 ? n : 56 + n);
            short8 bf0, bf1;
            const float* wp = w4b + outch * 64 + q * 8;
#pragma unroll
            for (int j = 0; j < 8; j++) bf0[j] = f2bs(wp[j]);
            wp += 32;
#pragma unroll
            for (int j = 0; j < 8; j++) bf1[j] = f2bs(wp[j]);
            float b4v = b4b[outch];
            for (int mt = wave; mt < 8; mt += 4) {
                const short* arow = &sX[(mt * 16 + n) * 72];
                short8 a0 = *(const short8*)(arow + q * 8);
                short8 a1 = *(const short8*)(arow + 32 + q * 8);
                f32x4 d = {0.f, 0.f, 0.f, 0.f};
                d = __builtin_amdgcn_mfma_f32_16x16x32_bf16(a0, bf0, d, 0, 0, 0);
                d = __builtin_amdgcn_mfma_f32_16x16x32_bf16(a1, bf1, d, 0, 0, 0);
#pragma unroll
                for (int r = 0; r < 4; r++) {
                    float val = d[r] + b4v;
                    float other = __shfl_xor(val, 8);
                    if (n < 8)
                        sH[(mt * 16 + q * 4 + r) * 72 + cc * 8 + n] = f2bs(val * other);
                }
            }
        }
    }
    __syncthreads();

    // phase 5: pw5 -> x5 -> sX
    {
        const float* w5b = ws + W5N_OFF + b * 64 * 64;
        const float* b5b = b5 + b * 64;
        for (int nc = 0; nc < 4; nc++) {
            int outch = nc * 16 + n;
            short8 bf0, bf1;
            const float* wp = w5b + outch * 64 + q * 8;
#pragma unroll
            for (int j = 0; j < 8; j++) bf0[j] = f2bs(wp[j]);
            wp += 32;
#pragma unroll
            for (int j = 0; j < 8; j++) bf1[j] = f2bs(wp[j]);
            float b5v = b5b[outch];
            for (int mt = wave; mt < 8; mt += 4) {
                const short* arow = &sH[(mt * 16 + n) * 72];
                short8 a0 = *(const short8*)(arow + q * 8);
                short8 a1 = *(const short8*)(arow + 32 + q * 8);
                f32x4 d = {0.f, 0.f, 0.f, 0.f};
                d = __builtin_amdgcn_mfma_f32_16x16x32_bf16(a0, bf0, d, 0, 0, 0);
                d = __builtin_amdgcn_mfma_f32_16x16x32_bf16(a1, bf1, d, 0, 0, 0);
#pragma unroll
                for (int r = 0; r < 4; r++)
                    sX[(mt * 16 + q * 4 + r) * 72 + outch] = f2bs(d[r] + b5v);
            }
        }
    }
    __syncthreads();

    // phase 6: out = y + gamma * x5
    {
        int px = t & 127, half = t >> 7;
        float* ob = out + ((size_t)b << 22) + px0;
        for (int c = half * 32; c < half * 32 + 32; c++) {
            float o = bs2f(sY[c * 136 + px]) + gamma[c] * bs2f(sX[px * 72 + c]);
            ob[((size_t)c << 16) + px] = o;
        }
    }
}

extern "C" void kernel_launch(void* const* d_in, const int* in_sizes, int n_in,
                              void* d_out, int out_size, void* d_ws, size_t ws_size,
                              hipStream_t stream) {
    const float* inp  = (const float*)d_in[0];
    const float* w1   = (const float*)d_in[1];
    const float* b1   = (const float*)d_in[2];
    const float* w2   = (const float*)d_in[3];
    const float* b2v  = (const float*)d_in[4];
    const float* w3   = (const float*)d_in[5];
    const float* b3   = (const float*)d_in[6];
    const float* w4   = (const float*)d_in[7];
    const float* b4   = (const float*)d_in[8];
    const float* w5   = (const float*)d_in[9];
    const float* b5   = (const float*)d_in[10];
    const float* ln1w = (const float*)d_in[11];
    const float* ln1b = (const float*)d_in[12];
    const float* ln2w = (const float*)d_in[13];
    const float* ln2b = (const float*)d_in[14];
    const float* scaw = (const float*)d_in[15];
    const float* scab = (const float*)d_in[16];
    const float* beta = (const float*)d_in[17];
    const float* gamma= (const float*)d_in[18];

    float* ws = (float*)d_ws;
    float* pooled = ws + POOL_OFF;
    float* sca = ws + SCA_OFF;
    float* g = (float*)d_out;   // d_out doubles as scratch for the gated tensor
    float* out = (float*)d_out;

    k_prep<<<16, 256, 0, stream>>>(w1, w2, w3, w4, w5, ws);
    k1<<<2048, 256, 0, stream>>>(inp, ln1w, ln1b, b1, b2v, ws, g);
    k_pool<<<512, 1024, 0, stream>>>(g, pooled);
    k_sca<<<1, 512, 0, stream>>>(pooled, scaw, scab, sca);
    k2<<<4096, 256, 0, stream>>>(inp, g, ws, b3, beta, ln2w, ln2b, b4, b5,
                                 gamma, out);
}